// Round 16
// baseline (65.274 us; speedup 1.0000x reference)
//
#include <hip/hip_runtime.h>

#define KBIN 160      // interpolation bins (bin width 5/160)
#define TSTRIDE 68    // packed-table row stride in uints (272 B)
#define TPSZ  10880   // uints per packed table (= KBIN*TSTRIDE)
#define FBASE 10880   // uint index of f-chunk buffer 0
#define FB2   14976   // uint index of f-chunk buffer 1 (FBASE + 4096)

typedef _Float16 half2v __attribute__((ext_vector_type(2)));

__device__ __forceinline__ float ssp(float x) {
    // softplus(x) - ln2, numerically stable
    return fmaxf(x, 0.0f) + log1pf(expf(-fabsf(x))) - 0.69314718055994531f;
}

__device__ __forceinline__ float bclane(float v, int l) {
    return __builtin_bit_cast(float, __builtin_amdgcn_readlane(__builtin_bit_cast(int, v), l));
}

// pack one pair: hi16 = k*272 (byte offset into packed table), lo16 = f16 frac
__device__ __forceinline__ unsigned int kaenc(float d) {
    float tv = fminf(fmaxf(d, 0.0f)*32.0f, 159.999f);
    int k = (int)tv;
    float fr = tv - (float)k;
    unsigned short fh = __builtin_bit_cast(unsigned short, (_Float16)fr);
    return ((unsigned int)(k*272) << 16) | (unsigned int)fh;
}

// out[lane] = sum_f bclane(x,f) * WT[lane][f]; WT swizzled, b128 conflict-free
__device__ __forceinline__ float matvec64(const float* __restrict__ ldsA, int base, float xv, int lane) {
    float a0 = 0.f, a1 = 0.f, a2 = 0.f, a3 = 0.f;
    #pragma unroll
    for (int gg = 0; gg < 16; ++gg) {
        const float4 w = *(const float4*)&ldsA[base + lane*64 + (((gg + lane) & 15) << 2)];
        a0 += bclane(xv, gg*4+0) * w.x;
        a1 += bclane(xv, gg*4+1) * w.y;
        a2 += bclane(xv, gg*4+2) * w.z;
        a3 += bclane(xv, gg*4+3) * w.w;
    }
    return (a0 + a1) + (a2 + a3);
}

// 2-row batched matvec (pre0 only)
__device__ __forceinline__ void matvec64x2(const float* __restrict__ ldsA, int base,
                                           float xv0, float xv1, int lane,
                                           float& o0, float& o1) {
    float a0 = 0.f, a1 = 0.f, b0 = 0.f, b1 = 0.f;
    #pragma unroll
    for (int gg = 0; gg < 16; ++gg) {
        const float4 w = *(const float4*)&ldsA[base + lane*64 + (((gg + lane) & 15) << 2)];
        a0 += bclane(xv0, gg*4+0) * w.x;
        a1 += bclane(xv0, gg*4+1) * w.y;
        a0 += bclane(xv0, gg*4+2) * w.z;
        a1 += bclane(xv0, gg*4+3) * w.w;
        b0 += bclane(xv1, gg*4+0) * w.x;
        b1 += bclane(xv1, gg*4+1) * w.y;
        b0 += bclane(xv1, gg*4+2) * w.z;
        b1 += bclane(xv1, gg*4+3) * w.w;
    }
    o0 = a0 + a1;
    o1 = b0 + b1;
}

__device__ __forceinline__ void stageWT(float* __restrict__ lds, int base, const float* __restrict__ W, int tid) {
    for (int s = tid; s < 4096; s += 512) {
        int f = s >> 6, g = s & 63;
        lds[base + g*64 + ((((f >> 2) + g) & 15) << 2) + (f & 3)] = W[s];
    }
}

// pre0: wgs [0,128): f0 = emb@in2f0 (2 rows/wave).
//       wgs [128,188): build+pack 3 tables (20 wgs per block, 8 bins each).
//       wgs [188,444): encode ka (k,frac) for all 1M pairs, 8 pairs/thread.
__global__ __launch_bounds__(512) void schnet_pre0(
    const float* __restrict__ emb, const float* __restrict__ dists,
    const float* __restrict__ in2f,
    const float* __restrict__ fw1, const float* __restrict__ fb1,
    const float* __restrict__ fw2, const float* __restrict__ fb2,
    unsigned short* __restrict__ f_out, unsigned int* __restrict__ Tp_g,
    unsigned int* __restrict__ ka)
{
    __shared__ float lds[12544];
    const int wg = blockIdx.x, tid = threadIdx.x;
    const int wave = tid >> 6, lane = tid & 63;
    if (wg < 128) {
        stageWT(lds, 0, in2f, tid);
        __syncthreads();
        int row0 = wg*16 + wave*2;
        size_t ro0 = (size_t)row0*64 + lane;
        size_t ro1 = ro0 + 64;
        float f0, f1;
        matvec64x2(lds, 0, emb[ro0], emb[ro1], lane, f0, f1);
        f_out[ro0] = __builtin_bit_cast(unsigned short, (_Float16)f0);
        f_out[ro1] = __builtin_bit_cast(unsigned short, (_Float16)f1);
    } else if (wg < 188) {
        // table build+pack: 20 wgs per tt, 8 bins each (bins 0..159)
        int widx = wg - 128;
        int tt = widx / 20;
        int k = (widx % 20)*8 + wave;
        const float* fw1t = fw1 + tt*25*64;
        const float* fw2t = fw2 + tt*64*64;
        for (int s = tid; s < 1600; s += 512) lds[s] = fw1t[s];
        for (int s = tid; s < 4096; s += 512) lds[1600 + s] = fw2t[s];
        if (tid < 64) { lds[5696 + tid] = fb1[tt*64 + tid]; lds[5760 + tid] = fb2[tt*64 + tid]; }
        __syncthreads();
        float T2[2];
        #pragma unroll
        for (int e = 0; e < 2; ++e) {
            float dk = (float)(k + e) * (5.0f/160.0f);
            float h1 = lds[5696 + lane];
            for (int r = 0; r < 25; ++r) {
                float sr = dk - (float)r * (5.0f/24.0f);
                h1 += expf(-10.0f*sr*sr) * lds[r*64 + lane];
            }
            float u = ssp(h1);
            float T = lds[5760 + lane];
            #pragma unroll
            for (int gg = 0; gg < 64; ++gg)
                T += bclane(u, gg) * lds[1600 + gg*64 + lane];
            T2[e] = T;
        }
        float* sc = &lds[5824 + wave*128];   // wave-private scratch (same-wave rd-after-wr)
        sc[lane] = T2[0];
        sc[64 + lane] = T2[1];
        if (lane < 16) {
            float4 A  = *(const float4*)&sc[lane*4];
            float4 Bv = *(const float4*)&sc[64 + lane*4];
            half2v t01 = { (_Float16)A.x, (_Float16)A.y };
            half2v t23 = { (_Float16)A.z, (_Float16)A.w };
            half2v d01 = { (_Float16)(Bv.x - A.x), (_Float16)(Bv.y - A.y) };
            half2v d23 = { (_Float16)(Bv.z - A.z), (_Float16)(Bv.w - A.w) };
            uint4 o;
            o.x = __builtin_bit_cast(unsigned int, t01);
            o.y = __builtin_bit_cast(unsigned int, t23);
            o.z = __builtin_bit_cast(unsigned int, d01);
            o.w = __builtin_bit_cast(unsigned int, d23);
            *(uint4*)&Tp_g[(size_t)tt*TPSZ + k*TSTRIDE + lane*4] = o;
        }
    } else {
        // ka encode: 256 wgs x 512 thr x 8 pairs
        size_t p = (size_t)(wg - 188)*4096 + (size_t)tid*8;
        float4 d0 = *(const float4*)&dists[p];
        float4 d1 = *(const float4*)&dists[p + 4];
        uint4 o0, o1;
        o0.x = kaenc(d0.x); o0.y = kaenc(d0.y); o0.z = kaenc(d0.z); o0.w = kaenc(d0.w);
        o1.x = kaenc(d1.x); o1.y = kaenc(d1.y); o1.z = kaenc(d1.z); o1.w = kaenc(d1.w);
        *(uint4*)&ka[p] = o0;
        *(uint4*)&ka[p + 4] = o1;
    }
}

// K(t): 512 wgs = (b 4) x (it 128). Each wg: 4 rows x ALL 512 j (4 chunks of 128),
// double-buffered f, prefetched kq, one barrier per chunk; then row-local post-MLP.
__global__ __launch_bounds__(512, 4) void schnet_block(
    int t,
    const float* __restrict__ emb,
    const float* __restrict__ in2f,
    const float* __restrict__ f2o, const float* __restrict__ f2b,
    const float* __restrict__ dw,  const float* __restrict__ db,
    const float* __restrict__ aw1, const float* __restrict__ ab1,
    const float* __restrict__ aw2, const float* __restrict__ ab2,
    const unsigned int* __restrict__ Tp_g,
    const unsigned int* __restrict__ ka,
    const unsigned short* __restrict__ f_in,
    unsigned short* __restrict__ f_out,
    float* __restrict__ x_buf, float* __restrict__ out)
{
    __shared__ unsigned int ldsu[FB2 + 4096];   // 19072 uints = 76288 B -> 2 wgs/CU
    float* lds = (float*)ldsu;
    const int wg = blockIdx.x, tid = threadIdx.x;
    const int wave = tid >> 6, lane = tid & 63;
    const int b = wg >> 7, it = wg & 127;
    const int i0 = it * 4;
    const int fq = lane & 15, g = lane >> 4;
    const int r = wave >> 1;          // row within tile (0..3)
    const int jhalf = wave & 1;       // 64-j half within chunk

    // copy this block's pre-packed table (overlaps f/kq prologue loads)
    const unsigned int* Tp = Tp_g + (size_t)t*TPSZ;
    for (int s = tid; s < TPSZ/4; s += 512)
        ((uint4*)ldsu)[s] = ((const uint4*)Tp)[s];

    // f staging: thread = (j0 = tid>>4, fq2 = tid&15); covers j = j0 + {0,32,64,96}.
    // Global: entry (j,fq2) = uint2 index j*16 + fq2. LDS: FBASE/FB2 + (j>>1)*64 + fq2*4 + (j&1)*2
    const int j0 = tid >> 4, fq2 = tid & 15;
    const uint2* fsrc0 = (const uint2*)f_in + ((size_t)b*512 + j0)*16 + fq2;
    const int fo_base = (j0 >> 1)*64 + fq2*4 + (j0 & 1)*2;
    unsigned int* fdstA = ldsu + FBASE + fo_base;
    unsigned int* fdstB = ldsu + FB2 + fo_base;
    const unsigned int* kabase = &ka[((size_t)(b*512 + i0 + r))*512 + jhalf*64 + g*16];

    uint2 rb0, rb1, rb2, rb3;
    uint4 kc0, kc1, kc2, kc3, kn0, kn1, kn2, kn3;
    // prologue: chunk 0 f + kq, write f -> buf0
    {
        rb0 = fsrc0[0]; rb1 = fsrc0[512]; rb2 = fsrc0[1024]; rb3 = fsrc0[1536];
        kc0 = ((const uint4*)kabase)[0];
        kc1 = ((const uint4*)kabase)[1];
        kc2 = ((const uint4*)kabase)[2];
        kc3 = ((const uint4*)kabase)[3];
        *(uint2*)fdstA = rb0; *(uint2*)(fdstA + 1024) = rb1;
        *(uint2*)(fdstA + 2048) = rb2; *(uint2*)(fdstA + 3072) = rb3;
    }
    __syncthreads();   // table + chunk 0 ready

    const unsigned int* fpA = ldsu + FBASE + fq*4;
    const unsigned int* fpB = ldsu + FB2 + fq*4;
    const char* Tbyte = (const char*)ldsu + fq*16;
    const int jpb = jhalf*32 + g*8;
    float a0 = 0.f, a1 = 0.f, a2 = 0.f, a3 = 0.f;

    #pragma unroll
    for (int c = 0; c < 4; ++c) {
        if (c < 3) {  // prefetch next chunk's f and kq (latency hides under compute)
            const uint2* sp = fsrc0 + (size_t)(c + 1)*2048;
            rb0 = sp[0]; rb1 = sp[512]; rb2 = sp[1024]; rb3 = sp[1536];
            const uint4* kp = (const uint4*)(kabase + (c + 1)*128);
            kn0 = kp[0]; kn1 = kp[1]; kn2 = kp[2]; kn3 = kp[3];
        }
        const unsigned int* fp = (c & 1) ? fpB : fpA;
        uint4 kqa[4] = {kc0, kc1, kc2, kc3};
        #pragma unroll
        for (int j4 = 0; j4 < 4; ++j4) {
            uint4 fA = *(const uint4*)&fp[(jpb + j4*2)*64];
            uint4 fB = *(const uint4*)&fp[(jpb + j4*2 + 1)*64];
            unsigned int kk[4] = {kqa[j4].x, kqa[j4].y, kqa[j4].z, kqa[j4].w};
            unsigned int fl_[8] = {fA.x, fA.y, fA.z, fA.w, fB.x, fB.y, fB.z, fB.w};
            #pragma unroll
            for (int u = 0; u < 4; ++u) {
                unsigned int kau = kk[u];
                unsigned int koff = kau >> 16;
                half2v av = __builtin_bit_cast(half2v, __builtin_amdgcn_perm(kau, kau, 0x01000100u));
                uint4 tp = *(const uint4*)(Tbyte + koff);
                half2v W01 = __builtin_bit_cast(half2v, tp.z)*av + __builtin_bit_cast(half2v, tp.x);
                half2v W23 = __builtin_bit_cast(half2v, tp.w)*av + __builtin_bit_cast(half2v, tp.y);
                half2v f01 = __builtin_bit_cast(half2v, fl_[u*2]);
                half2v f23 = __builtin_bit_cast(half2v, fl_[u*2+1]);
                a0 += (float)W01[0] * (float)f01[0];
                a1 += (float)W01[1] * (float)f01[1];
                a2 += (float)W23[0] * (float)f23[0];
                a3 += (float)W23[1] * (float)f23[1];
            }
        }
        if (c < 3) {
            // write next chunk into the other buffer (its previous contents were
            // consumed in chunk c-1; the barrier at end of c-1 made that global)
            unsigned int* fd = (c & 1) ? fdstA : fdstB;
            *(uint2*)fd = rb0; *(uint2*)(fd + 1024) = rb1;
            *(uint2*)(fd + 2048) = rb2; *(uint2*)(fd + 3072) = rb3;
            kc0 = kn0; kc1 = kn1; kc2 = kn2; kc3 = kn3;
            __syncthreads();   // chunk c+1 visible to all
        }
    }
    // reduce over g (4 sub-groups) in-wave
    a0 += __shfl_xor(a0, 16, 64); a0 += __shfl_xor(a0, 32, 64);
    a1 += __shfl_xor(a1, 16, 64); a1 += __shfl_xor(a1, 32, 64);
    a2 += __shfl_xor(a2, 16, 64); a2 += __shfl_xor(a2, 32, 64);
    a3 += __shfl_xor(a3, 16, 64); a3 += __shfl_xor(a3, 32, 64);

    __syncthreads();                  // all conv LDS reads done; regions reusable
    if (g == 0) {                     // y half-row per wave -> scratch in buf1 region
        float4 acc; acc.x = a0; acc.y = a1; acc.z = a2; acc.w = a3;
        *(float4*)&lds[FB2 + wave*64 + fq*4] = acc;
    }
    // stage post weights (table + buf0 regions are dead now)
    stageWT(lds, 0, f2o + t*4096, tid);
    stageWT(lds, 4096, dw + t*4096, tid);
    if (t < 2) {
        stageWT(lds, 8192, in2f + (t+1)*4096, tid);
    } else {
        for (int s = tid; s < 4096; s += 512) {   // aw1^T dup to 64 rows, swizzled
            int f = s >> 6, rr = s & 63;
            lds[8192 + rr*64 + ((((f >> 2) + rr) & 15) << 2) + (f & 3)] = aw1[f*32 + (rr & 31)];
        }
    }
    if (tid < 64) {
        lds[12288 + tid] = f2b[t*64 + tid];
        lds[12352 + tid] = db[t*64 + tid];
        if (t == 2) {
            lds[12416 + tid] = ab1[tid & 31];
            lds[12480 + tid] = aw2[tid & 31];
        }
    }
    __syncthreads();

    if (wave < 4) {                   // row-local post: wave w handles row i0+w
        int grow = b*512 + i0 + wave;
        size_t ro = (size_t)grow*64 + lane;
        float y = lds[FB2 + (wave*2)*64 + lane] + lds[FB2 + (wave*2+1)*64 + lane];
        float z = matvec64(lds, 0, y, lane) + lds[12288 + lane];
        float u = ssp(z);
        float y3 = matvec64(lds, 4096, u, lane) + lds[12352 + lane];
        float xin = (t == 0) ? emb[ro] : x_buf[ro];
        float xn = xin + y3;
        if (t < 2) {
            x_buf[ro] = xn;
            float fo = matvec64(lds, 8192, xn, lane);
            f_out[ro] = __builtin_bit_cast(unsigned short, (_Float16)fo);
        } else {
            float s1 = matvec64(lds, 8192, xn, lane) + lds[12416 + lane];
            float h = ssp(s1) * lds[12480 + lane];
            #pragma unroll
            for (int m = 1; m < 64; m <<= 1)
                h += __shfl_xor(h, m, 64);
            if (lane == 0) out[grow] = ab2[0] + 0.5f*h;   // lanes duplicate 32-dim h twice
        }
    }
}

extern "C" void kernel_launch(void* const* d_in, const int* in_sizes, int n_in,
                              void* d_out, int out_size, void* d_ws, size_t ws_size,
                              hipStream_t stream) {
    const float* emb  = (const float*)d_in[0];
    const float* dist = (const float*)d_in[1];
    const float* in2f = (const float*)d_in[2];
    const float* fw1  = (const float*)d_in[3];
    const float* fb1  = (const float*)d_in[4];
    const float* fw2  = (const float*)d_in[5];
    const float* fb2  = (const float*)d_in[6];
    const float* f2o  = (const float*)d_in[7];
    const float* f2b  = (const float*)d_in[8];
    const float* dwp  = (const float*)d_in[9];
    const float* dbp  = (const float*)d_in[10];
    const float* aw1  = (const float*)d_in[11];
    const float* ab1  = (const float*)d_in[12];
    const float* aw2  = (const float*)d_in[13];
    const float* ab2  = (const float*)d_in[14];
    float* out = (float*)d_out;
    float* ws = (float*)d_ws;
    unsigned int* Tp_g = (unsigned int*)ws;                  // 3*10880 = 32640 uints
    unsigned short* fA = (unsigned short*)(ws + 32640);      // 65536 float slots
    unsigned short* fB = (unsigned short*)(ws + 32640 + 65536);
    float* x_buf = ws + 32640 + 2*65536;                     // 131072 floats
    unsigned int* ka = (unsigned int*)(x_buf + 131072);      // 1048576 uints (4 MB)

    hipLaunchKernelGGL(schnet_pre0, dim3(444), dim3(512), 0, stream,
        emb, dist, in2f, fw1, fb1, fw2, fb2, fA, Tp_g, ka);
    hipLaunchKernelGGL(schnet_block, dim3(512), dim3(512), 0, stream,
        0, emb, in2f, f2o, f2b, dwp, dbp, aw1, ab1, aw2, ab2,
        Tp_g, ka, fA, fB, x_buf, out);
    hipLaunchKernelGGL(schnet_block, dim3(512), dim3(512), 0, stream,
        1, emb, in2f, f2o, f2b, dwp, dbp, aw1, ab1, aw2, ab2,
        Tp_g, ka, fB, fA, x_buf, out);
    hipLaunchKernelGGL(schnet_block, dim3(512), dim3(512), 0, stream,
        2, emb, in2f, f2o, f2b, dwp, dbp, aw1, ab1, aw2, ab2,
        Tp_g, ka, fA, fB, x_buf, out);
}

// Round 17
// 61.806 us; speedup vs baseline: 1.0561x; 1.0561x over previous
//
#include <hip/hip_runtime.h>

#define KBIN 128      // interpolation bins (width 5/128)
#define TSTRIDE 68    // packed-table row stride in uints (272 B)
#define TPSZ  8704    // uints per packed table (= KBIN*TSTRIDE)
#define FBASE 8704    // uint index of f-chunk buffer 0
#define FB2   12800   // uint index of f-chunk buffer 1 (FBASE + 4096)

typedef _Float16 half2v __attribute__((ext_vector_type(2)));

__device__ __forceinline__ float ssp(float x) {
    // softplus(x) - ln2, numerically stable
    return fmaxf(x, 0.0f) + log1pf(expf(-fabsf(x))) - 0.69314718055994531f;
}

__device__ __forceinline__ float bclane(float v, int l) {
    return __builtin_bit_cast(float, __builtin_amdgcn_readlane(__builtin_bit_cast(int, v), l));
}

// pack one pair: hi16 = k*272 (byte offset into packed table), lo16 = f16 frac
__device__ __forceinline__ unsigned int kaenc(float d) {
    float tv = fminf(fmaxf(d, 0.0f)*25.6f, 127.999f);
    int k = (int)tv;
    float fr = tv - (float)k;
    unsigned short fh = __builtin_bit_cast(unsigned short, (_Float16)fr);
    return ((unsigned int)(k*272) << 16) | (unsigned int)fh;
}

// out[lane] = sum_f bclane(x,f) * WT[lane][f]; WT swizzled, b128 conflict-free
__device__ __forceinline__ float matvec64(const float* __restrict__ ldsA, int base, float xv, int lane) {
    float a0 = 0.f, a1 = 0.f, a2 = 0.f, a3 = 0.f;
    #pragma unroll
    for (int gg = 0; gg < 16; ++gg) {
        const float4 w = *(const float4*)&ldsA[base + lane*64 + (((gg + lane) & 15) << 2)];
        a0 += bclane(xv, gg*4+0) * w.x;
        a1 += bclane(xv, gg*4+1) * w.y;
        a2 += bclane(xv, gg*4+2) * w.z;
        a3 += bclane(xv, gg*4+3) * w.w;
    }
    return (a0 + a1) + (a2 + a3);
}

// 2-row batched matvec (pre0 only)
__device__ __forceinline__ void matvec64x2(const float* __restrict__ ldsA, int base,
                                           float xv0, float xv1, int lane,
                                           float& o0, float& o1) {
    float a0 = 0.f, a1 = 0.f, b0 = 0.f, b1 = 0.f;
    #pragma unroll
    for (int gg = 0; gg < 16; ++gg) {
        const float4 w = *(const float4*)&ldsA[base + lane*64 + (((gg + lane) & 15) << 2)];
        a0 += bclane(xv0, gg*4+0) * w.x;
        a1 += bclane(xv0, gg*4+1) * w.y;
        a0 += bclane(xv0, gg*4+2) * w.z;
        a1 += bclane(xv0, gg*4+3) * w.w;
        b0 += bclane(xv1, gg*4+0) * w.x;
        b1 += bclane(xv1, gg*4+1) * w.y;
        b0 += bclane(xv1, gg*4+2) * w.z;
        b1 += bclane(xv1, gg*4+3) * w.w;
    }
    o0 = a0 + a1;
    o1 = b0 + b1;
}

// vectorized swizzled weight stage: W row-major [f][g] -> WT[g][f] swizzled, b128 writes
__device__ __forceinline__ void stageWT4(float* __restrict__ lds, int base, const float* __restrict__ W, int tid) {
    for (int s = tid; s < 1024; s += 512) {
        int quad = s >> 6, g = s & 63;
        float4 v;
        v.x = W[(quad*4+0)*64 + g];
        v.y = W[(quad*4+1)*64 + g];
        v.z = W[(quad*4+2)*64 + g];
        v.w = W[(quad*4+3)*64 + g];
        *(float4*)&lds[base + g*64 + (((quad + g) & 15) << 2)] = v;
    }
}

// pre0: wgs [0,128): f0 = emb@in2f0 (2 rows/wave). wgs [128,176): build+pack 3 tables.
__global__ __launch_bounds__(512) void schnet_pre0(
    const float* __restrict__ emb,
    const float* __restrict__ in2f,
    const float* __restrict__ fw1, const float* __restrict__ fb1,
    const float* __restrict__ fw2, const float* __restrict__ fb2,
    unsigned short* __restrict__ f_out, unsigned int* __restrict__ Tp_g)
{
    __shared__ float lds[12544];
    const int wg = blockIdx.x, tid = threadIdx.x;
    const int wave = tid >> 6, lane = tid & 63;
    if (wg < 128) {
        stageWT4(lds, 0, in2f, tid);
        __syncthreads();
        int row0 = wg*16 + wave*2;
        size_t ro0 = (size_t)row0*64 + lane;
        size_t ro1 = ro0 + 64;
        float f0, f1;
        matvec64x2(lds, 0, emb[ro0], emb[ro1], lane, f0, f1);
        f_out[ro0] = __builtin_bit_cast(unsigned short, (_Float16)f0);
        f_out[ro1] = __builtin_bit_cast(unsigned short, (_Float16)f1);
    } else {
        // table build+pack: 16 wgs per tt, 8 bins each (bins 0..127)
        int widx = wg - 128;
        int tt = widx / 16;
        int k = (widx % 16)*8 + wave;
        const float* fw1t = fw1 + tt*25*64;
        const float* fw2t = fw2 + tt*64*64;
        for (int s = tid; s < 1600; s += 512) lds[s] = fw1t[s];
        for (int s = tid; s < 4096; s += 512) lds[1600 + s] = fw2t[s];
        if (tid < 64) { lds[5696 + tid] = fb1[tt*64 + tid]; lds[5760 + tid] = fb2[tt*64 + tid]; }
        __syncthreads();
        float T2[2];
        #pragma unroll
        for (int e = 0; e < 2; ++e) {
            float dk = (float)(k + e) * (5.0f/128.0f);
            float h1 = lds[5696 + lane];
            for (int r = 0; r < 25; ++r) {
                float sr = dk - (float)r * (5.0f/24.0f);
                h1 += expf(-10.0f*sr*sr) * lds[r*64 + lane];
            }
            float u = ssp(h1);
            float T = lds[5760 + lane];
            #pragma unroll
            for (int gg = 0; gg < 64; ++gg)
                T += bclane(u, gg) * lds[1600 + gg*64 + lane];
            T2[e] = T;
        }
        float* sc = &lds[5824 + wave*128];   // wave-private scratch (same-wave rd-after-wr)
        sc[lane] = T2[0];
        sc[64 + lane] = T2[1];
        if (lane < 16) {
            float4 A  = *(const float4*)&sc[lane*4];
            float4 Bv = *(const float4*)&sc[64 + lane*4];
            half2v t01 = { (_Float16)A.x, (_Float16)A.y };
            half2v t23 = { (_Float16)A.z, (_Float16)A.w };
            half2v d01 = { (_Float16)(Bv.x - A.x), (_Float16)(Bv.y - A.y) };
            half2v d23 = { (_Float16)(Bv.z - A.z), (_Float16)(Bv.w - A.w) };
            uint4 o;
            o.x = __builtin_bit_cast(unsigned int, t01);
            o.y = __builtin_bit_cast(unsigned int, t23);
            o.z = __builtin_bit_cast(unsigned int, d01);
            o.w = __builtin_bit_cast(unsigned int, d23);
            *(uint4*)&Tp_g[(size_t)tt*TPSZ + k*TSTRIDE + lane*4] = o;
        }
    }
}

// K(t): 512 wgs = (b 4) x (it 128). Each wg: 4 rows x ALL 512 j (4 chunks of 128),
// double-buffered f, prefetched kq; t==0 also encodes its own ka rows (row-local).
__global__ __launch_bounds__(512, 4) void schnet_block(
    int t,
    const float* __restrict__ emb, const float* __restrict__ dists,
    const float* __restrict__ in2f,
    const float* __restrict__ f2o, const float* __restrict__ f2b,
    const float* __restrict__ dw,  const float* __restrict__ db,
    const float* __restrict__ aw1, const float* __restrict__ ab1,
    const float* __restrict__ aw2, const float* __restrict__ ab2,
    const unsigned int* __restrict__ Tp_g,
    unsigned int* __restrict__ ka,
    const unsigned short* __restrict__ f_in,
    unsigned short* __restrict__ f_out,
    float* __restrict__ x_buf, float* __restrict__ out)
{
    __shared__ unsigned int ldsu[FB2 + 4096];   // 16896 uints = 67.6 KB -> 2 wgs/CU
    float* lds = (float*)ldsu;
    const int wg = blockIdx.x, tid = threadIdx.x;
    const int wave = tid >> 6, lane = tid & 63;
    const int b = wg >> 7, it = wg & 127;
    const int i0 = it * 4;
    const int fq = lane & 15, g = lane >> 4;
    const int r = wave >> 1;          // row within tile (0..3)
    const int jhalf = wave & 1;       // 64-j half within chunk

    // copy this block's pre-packed table (overlaps other prologue loads)
    const unsigned int* Tp = Tp_g + (size_t)t*TPSZ;
    for (int s = tid; s < TPSZ/4; s += 512)
        ((uint4*)ldsu)[s] = ((const uint4*)Tp)[s];

    // t==0: encode this wg's own ka rows (4 rows x 512 j), row-local
    if (t == 0) {
        int erow = tid >> 7;                 // 0..3
        int ecol = (tid & 127) * 4;
        size_t ep = ((size_t)(b*512 + i0 + erow))*512 + ecol;
        float4 dv = *(const float4*)&dists[ep];
        uint4 eo;
        eo.x = kaenc(dv.x); eo.y = kaenc(dv.y); eo.z = kaenc(dv.z); eo.w = kaenc(dv.w);
        *(uint4*)&ka[ep] = eo;
    }

    // f staging: thread = (j0 = tid>>4, fq2 = tid&15); covers j = j0 + {0,32,64,96}.
    const int j0 = tid >> 4, fq2 = tid & 15;
    const uint2* fsrc0 = (const uint2*)f_in + ((size_t)b*512 + j0)*16 + fq2;
    const int fo_base = (j0 >> 1)*64 + fq2*4 + (j0 & 1)*2;
    unsigned int* fdstA = ldsu + FBASE + fo_base;
    unsigned int* fdstB = ldsu + FB2 + fo_base;
    const unsigned int* kabase = &ka[((size_t)(b*512 + i0 + r))*512 + jhalf*64 + g*16];

    uint2 rb0, rb1, rb2, rb3;
    uint4 kc0, kc1, kc2, kc3, kn0, kn1, kn2, kn3;
    // prologue: chunk 0 f, write -> buf0; kq chunk0 (t>0 early, t==0 after barrier)
    {
        rb0 = fsrc0[0]; rb1 = fsrc0[512]; rb2 = fsrc0[1024]; rb3 = fsrc0[1536];
        if (t > 0) {
            kc0 = ((const uint4*)kabase)[0];
            kc1 = ((const uint4*)kabase)[1];
            kc2 = ((const uint4*)kabase)[2];
            kc3 = ((const uint4*)kabase)[3];
        }
        *(uint2*)fdstA = rb0; *(uint2*)(fdstA + 1024) = rb1;
        *(uint2*)(fdstA + 2048) = rb2; *(uint2*)(fdstA + 3072) = rb3;
    }
    __syncthreads();   // table + chunk 0 ready; vmcnt drained -> ka writes visible in-wg
    if (t == 0) {
        kc0 = ((const uint4*)kabase)[0];
        kc1 = ((const uint4*)kabase)[1];
        kc2 = ((const uint4*)kabase)[2];
        kc3 = ((const uint4*)kabase)[3];
    }

    const unsigned int* fpA = ldsu + FBASE + fq*4;
    const unsigned int* fpB = ldsu + FB2 + fq*4;
    const char* Tbyte = (const char*)ldsu + fq*16;
    const int jpb = jhalf*32 + g*8;
    float a0 = 0.f, a1 = 0.f, a2 = 0.f, a3 = 0.f;

    #pragma unroll
    for (int c = 0; c < 4; ++c) {
        if (c < 3) {  // prefetch next chunk's f and kq
            const uint2* sp = fsrc0 + (size_t)(c + 1)*2048;
            rb0 = sp[0]; rb1 = sp[512]; rb2 = sp[1024]; rb3 = sp[1536];
            const uint4* kp = (const uint4*)(kabase + (c + 1)*128);
            kn0 = kp[0]; kn1 = kp[1]; kn2 = kp[2]; kn3 = kp[3];
        }
        const unsigned int* fp = (c & 1) ? fpB : fpA;
        uint4 kqa[4] = {kc0, kc1, kc2, kc3};
        #pragma unroll
        for (int j4 = 0; j4 < 4; ++j4) {
            uint4 fA = *(const uint4*)&fp[(jpb + j4*2)*64];
            uint4 fB = *(const uint4*)&fp[(jpb + j4*2 + 1)*64];
            unsigned int kk[4] = {kqa[j4].x, kqa[j4].y, kqa[j4].z, kqa[j4].w};
            unsigned int fl_[8] = {fA.x, fA.y, fA.z, fA.w, fB.x, fB.y, fB.z, fB.w};
            #pragma unroll
            for (int u = 0; u < 4; ++u) {
                unsigned int kau = kk[u];
                unsigned int koff = kau >> 16;
                half2v av = __builtin_bit_cast(half2v, __builtin_amdgcn_perm(kau, kau, 0x01000100u));
                uint4 tp = *(const uint4*)(Tbyte + koff);
                half2v W01 = __builtin_bit_cast(half2v, tp.z)*av + __builtin_bit_cast(half2v, tp.x);
                half2v W23 = __builtin_bit_cast(half2v, tp.w)*av + __builtin_bit_cast(half2v, tp.y);
                half2v f01 = __builtin_bit_cast(half2v, fl_[u*2]);
                half2v f23 = __builtin_bit_cast(half2v, fl_[u*2+1]);
                a0 += (float)W01[0] * (float)f01[0];
                a1 += (float)W01[1] * (float)f01[1];
                a2 += (float)W23[0] * (float)f23[0];
                a3 += (float)W23[1] * (float)f23[1];
            }
        }
        if (c < 3) {
            unsigned int* fd = (c & 1) ? fdstA : fdstB;
            *(uint2*)fd = rb0; *(uint2*)(fd + 1024) = rb1;
            *(uint2*)(fd + 2048) = rb2; *(uint2*)(fd + 3072) = rb3;
            kc0 = kn0; kc1 = kn1; kc2 = kn2; kc3 = kn3;
            __syncthreads();   // chunk c+1 visible to all
        }
    }
    // reduce over g (4 sub-groups) in-wave
    a0 += __shfl_xor(a0, 16, 64); a0 += __shfl_xor(a0, 32, 64);
    a1 += __shfl_xor(a1, 16, 64); a1 += __shfl_xor(a1, 32, 64);
    a2 += __shfl_xor(a2, 16, 64); a2 += __shfl_xor(a2, 32, 64);
    a3 += __shfl_xor(a3, 16, 64); a3 += __shfl_xor(a3, 32, 64);

    __syncthreads();                  // all conv LDS reads done; regions reusable
    if (g == 0) {                     // y half-row per wave -> scratch in buf1 region
        float4 acc; acc.x = a0; acc.y = a1; acc.z = a2; acc.w = a3;
        *(float4*)&lds[FB2 + wave*64 + fq*4] = acc;
    }
    // stage post weights (table + buf0 regions are dead now)
    stageWT4(lds, 0, f2o + t*4096, tid);
    stageWT4(lds, 4096, dw + t*4096, tid);
    if (t < 2) {
        stageWT4(lds, 8192, in2f + (t+1)*4096, tid);
    } else {
        for (int s = tid; s < 1024; s += 512) {   // aw1^T dup to 64 rows, swizzled b128
            int quad = s >> 6, rr = s & 63;
            float4 v;
            v.x = aw1[(quad*4+0)*32 + (rr & 31)];
            v.y = aw1[(quad*4+1)*32 + (rr & 31)];
            v.z = aw1[(quad*4+2)*32 + (rr & 31)];
            v.w = aw1[(quad*4+3)*32 + (rr & 31)];
            *(float4*)&lds[8192 + rr*64 + (((quad + rr) & 15) << 2)] = v;
        }
    }
    if (tid < 64) {
        lds[12288 + tid] = f2b[t*64 + tid];
        lds[12352 + tid] = db[t*64 + tid];
        if (t == 2) {
            lds[12416 + tid] = ab1[tid & 31];
            lds[12480 + tid] = aw2[tid & 31];
        }
    }
    __syncthreads();

    if (wave < 4) {                   // row-local post: wave w handles row i0+w
        int grow = b*512 + i0 + wave;
        size_t ro = (size_t)grow*64 + lane;
        float y = lds[FB2 + (wave*2)*64 + lane] + lds[FB2 + (wave*2+1)*64 + lane];
        float z = matvec64(lds, 0, y, lane) + lds[12288 + lane];
        float u = ssp(z);
        float y3 = matvec64(lds, 4096, u, lane) + lds[12352 + lane];
        float xin = (t == 0) ? emb[ro] : x_buf[ro];
        float xn = xin + y3;
        if (t < 2) {
            x_buf[ro] = xn;
            float fo = matvec64(lds, 8192, xn, lane);
            f_out[ro] = __builtin_bit_cast(unsigned short, (_Float16)fo);
        } else {
            float s1 = matvec64(lds, 8192, xn, lane) + lds[12416 + lane];
            float h = ssp(s1) * lds[12480 + lane];
            #pragma unroll
            for (int m = 1; m < 64; m <<= 1)
                h += __shfl_xor(h, m, 64);
            if (lane == 0) out[grow] = ab2[0] + 0.5f*h;   // lanes duplicate 32-dim h twice
        }
    }
}

extern "C" void kernel_launch(void* const* d_in, const int* in_sizes, int n_in,
                              void* d_out, int out_size, void* d_ws, size_t ws_size,
                              hipStream_t stream) {
    const float* emb  = (const float*)d_in[0];
    const float* dist = (const float*)d_in[1];
    const float* in2f = (const float*)d_in[2];
    const float* fw1  = (const float*)d_in[3];
    const float* fb1  = (const float*)d_in[4];
    const float* fw2  = (const float*)d_in[5];
    const float* fb2  = (const float*)d_in[6];
    const float* f2o  = (const float*)d_in[7];
    const float* f2b  = (const float*)d_in[8];
    const float* dwp  = (const float*)d_in[9];
    const float* dbp  = (const float*)d_in[10];
    const float* aw1  = (const float*)d_in[11];
    const float* ab1  = (const float*)d_in[12];
    const float* aw2  = (const float*)d_in[13];
    const float* ab2  = (const float*)d_in[14];
    float* out = (float*)d_out;
    float* ws = (float*)d_ws;
    unsigned int* Tp_g = (unsigned int*)ws;                  // 3*8704 = 26112 uints
    unsigned short* fA = (unsigned short*)(ws + 26112);      // 65536 float slots
    unsigned short* fB = (unsigned short*)(ws + 26112 + 65536);
    float* x_buf = ws + 26112 + 2*65536;                     // 131072 floats
    unsigned int* ka = (unsigned int*)(x_buf + 131072);      // 1048576 uints (4 MB)

    hipLaunchKernelGGL(schnet_pre0, dim3(176), dim3(512), 0, stream,
        emb, in2f, fw1, fb1, fw2, fb2, fA, Tp_g);
    hipLaunchKernelGGL(schnet_block, dim3(512), dim3(512), 0, stream,
        0, emb, dist, in2f, f2o, f2b, dwp, dbp, aw1, ab1, aw2, ab2,
        Tp_g, ka, fA, fB, x_buf, out);
    hipLaunchKernelGGL(schnet_block, dim3(512), dim3(512), 0, stream,
        1, emb, dist, in2f, f2o, f2b, dwp, dbp, aw1, ab1, aw2, ab2,
        Tp_g, ka, fB, fA, x_buf, out);
    hipLaunchKernelGGL(schnet_block, dim3(512), dim3(512), 0, stream,
        2, emb, dist, in2f, f2o, f2b, dwp, dbp, aw1, ab1, aw2, ab2,
        Tp_g, ka, fA, fB, x_buf, out);
}

// Round 18
// 60.118 us; speedup vs baseline: 1.0858x; 1.0281x over previous
//
#include <hip/hip_runtime.h>

#define KBIN 128      // interpolation bins (width 5/128)
#define TSTRIDE 68    // packed-table row stride in uints (272 B)
#define TPSZ  8704    // uints per packed table (= KBIN*TSTRIDE)
#define FBASE 8704    // uint index of f-chunk buffer 0
#define FB2   12800   // uint index of f-chunk buffer 1 (FBASE + 4096)
#define YSCR  12800   // float index of y reduction scratch (reuses buf1 after conv)

typedef _Float16 half2v __attribute__((ext_vector_type(2)));

__device__ __forceinline__ float ssp(float x) {
    // softplus(x) - ln2, numerically stable
    return fmaxf(x, 0.0f) + log1pf(expf(-fabsf(x))) - 0.69314718055994531f;
}

__device__ __forceinline__ float bclane(float v, int l) {
    return __builtin_bit_cast(float, __builtin_amdgcn_readlane(__builtin_bit_cast(int, v), l));
}

// pack one pair: hi16 = k*272 (byte offset into packed table), lo16 = f16 frac
__device__ __forceinline__ unsigned int kaenc(float d) {
    float tv = fminf(fmaxf(d, 0.0f)*25.6f, 127.999f);
    int k = (int)tv;
    float fr = tv - (float)k;
    unsigned short fh = __builtin_bit_cast(unsigned short, (_Float16)fr);
    return ((unsigned int)(k*272) << 16) | (unsigned int)fh;
}

// out[lane] = sum_f bclane(x,f) * WT[lane][f]; WT swizzled, b128 conflict-free
__device__ __forceinline__ float matvec64(const float* __restrict__ ldsA, int base, float xv, int lane) {
    float a0 = 0.f, a1 = 0.f, a2 = 0.f, a3 = 0.f;
    #pragma unroll
    for (int gg = 0; gg < 16; ++gg) {
        const float4 w = *(const float4*)&ldsA[base + lane*64 + (((gg + lane) & 15) << 2)];
        a0 += bclane(xv, gg*4+0) * w.x;
        a1 += bclane(xv, gg*4+1) * w.y;
        a2 += bclane(xv, gg*4+2) * w.z;
        a3 += bclane(xv, gg*4+3) * w.w;
    }
    return (a0 + a1) + (a2 + a3);
}

// 2-row batched matvec (pre0 only)
__device__ __forceinline__ void matvec64x2(const float* __restrict__ ldsA, int base,
                                           float xv0, float xv1, int lane,
                                           float& o0, float& o1) {
    float a0 = 0.f, a1 = 0.f, b0 = 0.f, b1 = 0.f;
    #pragma unroll
    for (int gg = 0; gg < 16; ++gg) {
        const float4 w = *(const float4*)&ldsA[base + lane*64 + (((gg + lane) & 15) << 2)];
        a0 += bclane(xv0, gg*4+0) * w.x;
        a1 += bclane(xv0, gg*4+1) * w.y;
        a0 += bclane(xv0, gg*4+2) * w.z;
        a1 += bclane(xv0, gg*4+3) * w.w;
        b0 += bclane(xv1, gg*4+0) * w.x;
        b1 += bclane(xv1, gg*4+1) * w.y;
        b0 += bclane(xv1, gg*4+2) * w.z;
        b1 += bclane(xv1, gg*4+3) * w.w;
    }
    o0 = a0 + a1;
    o1 = b0 + b1;
}

// vectorized swizzled weight stage: W row-major [f][g] -> WT[g][f] swizzled, b128 writes
__device__ __forceinline__ void stageWT4(float* __restrict__ lds, int base, const float* __restrict__ W, int tid) {
    for (int s = tid; s < 1024; s += 512) {
        int quad = s >> 6, g = s & 63;
        float4 v;
        v.x = W[(quad*4+0)*64 + g];
        v.y = W[(quad*4+1)*64 + g];
        v.z = W[(quad*4+2)*64 + g];
        v.w = W[(quad*4+3)*64 + g];
        *(float4*)&lds[base + g*64 + (((quad + g) & 15) << 2)] = v;
    }
}

// pre0: wgs [0,128): f0 = emb@in2f0 (2 rows/wave). wgs [128,176): build+pack 3 tables.
__global__ __launch_bounds__(512) void schnet_pre0(
    const float* __restrict__ emb,
    const float* __restrict__ in2f,
    const float* __restrict__ fw1, const float* __restrict__ fb1,
    const float* __restrict__ fw2, const float* __restrict__ fb2,
    unsigned short* __restrict__ f_out, unsigned int* __restrict__ Tp_g)
{
    __shared__ float lds[12544];
    const int wg = blockIdx.x, tid = threadIdx.x;
    const int wave = tid >> 6, lane = tid & 63;
    if (wg < 128) {
        stageWT4(lds, 0, in2f, tid);
        __syncthreads();
        int row0 = wg*16 + wave*2;
        size_t ro0 = (size_t)row0*64 + lane;
        size_t ro1 = ro0 + 64;
        float f0, f1;
        matvec64x2(lds, 0, emb[ro0], emb[ro1], lane, f0, f1);
        f_out[ro0] = __builtin_bit_cast(unsigned short, (_Float16)f0);
        f_out[ro1] = __builtin_bit_cast(unsigned short, (_Float16)f1);
    } else {
        // table build+pack: 16 wgs per tt, 8 bins each (bins 0..127)
        int widx = wg - 128;
        int tt = widx / 16;
        int k = (widx % 16)*8 + wave;
        const float* fw1t = fw1 + tt*25*64;
        const float* fw2t = fw2 + tt*64*64;
        for (int s = tid; s < 1600; s += 512) lds[s] = fw1t[s];
        for (int s = tid; s < 4096; s += 512) lds[1600 + s] = fw2t[s];
        if (tid < 64) { lds[5696 + tid] = fb1[tt*64 + tid]; lds[5760 + tid] = fb2[tt*64 + tid]; }
        __syncthreads();
        float T2[2];
        #pragma unroll
        for (int e = 0; e < 2; ++e) {
            float dk = (float)(k + e) * (5.0f/128.0f);
            float h1 = lds[5696 + lane];
            for (int r = 0; r < 25; ++r) {
                float sr = dk - (float)r * (5.0f/24.0f);
                h1 += expf(-10.0f*sr*sr) * lds[r*64 + lane];
            }
            float u = ssp(h1);
            float T = lds[5760 + lane];
            #pragma unroll
            for (int gg = 0; gg < 64; ++gg)
                T += bclane(u, gg) * lds[1600 + gg*64 + lane];
            T2[e] = T;
        }
        float* sc = &lds[5824 + wave*128];   // wave-private scratch (same-wave rd-after-wr)
        sc[lane] = T2[0];
        sc[64 + lane] = T2[1];
        if (lane < 16) {
            float4 A  = *(const float4*)&sc[lane*4];
            float4 Bv = *(const float4*)&sc[64 + lane*4];
            half2v t01 = { (_Float16)A.x, (_Float16)A.y };
            half2v t23 = { (_Float16)A.z, (_Float16)A.w };
            half2v d01 = { (_Float16)(Bv.x - A.x), (_Float16)(Bv.y - A.y) };
            half2v d23 = { (_Float16)(Bv.z - A.z), (_Float16)(Bv.w - A.w) };
            uint4 o;
            o.x = __builtin_bit_cast(unsigned int, t01);
            o.y = __builtin_bit_cast(unsigned int, t23);
            o.z = __builtin_bit_cast(unsigned int, d01);
            o.w = __builtin_bit_cast(unsigned int, d23);
            *(uint4*)&Tp_g[(size_t)tt*TPSZ + k*TSTRIDE + lane*4] = o;
        }
    }
}

// K(t): 512 wgs = (b 4) x (it 128). Each wg: 4 rows x ALL 512 j (4 chunks of 128).
// Wave = 2 rows x 32 j; each 16-lane group = 2 rows x 8 j -> f-reads shared across rows.
__global__ __launch_bounds__(512, 4) void schnet_block(
    int t,
    const float* __restrict__ emb, const float* __restrict__ dists,
    const float* __restrict__ in2f,
    const float* __restrict__ f2o, const float* __restrict__ f2b,
    const float* __restrict__ dw,  const float* __restrict__ db,
    const float* __restrict__ aw1, const float* __restrict__ ab1,
    const float* __restrict__ aw2, const float* __restrict__ ab2,
    const unsigned int* __restrict__ Tp_g,
    unsigned int* __restrict__ ka,
    const unsigned short* __restrict__ f_in,
    unsigned short* __restrict__ f_out,
    float* __restrict__ x_buf, float* __restrict__ out)
{
    __shared__ unsigned int ldsu[FB2 + 4096];   // 16896 uints = 67.6 KB -> 2 wgs/CU
    float* lds = (float*)ldsu;
    const int wg = blockIdx.x, tid = threadIdx.x;
    const int wave = tid >> 6, lane = tid & 63;
    const int b = wg >> 7, it = wg & 127;
    const int i0 = it * 4;
    const int fq = lane & 15, g = lane >> 4;
    const int rp = wave & 1;          // row pair: rows {2rp, 2rp+1}
    const int jq = wave >> 1;         // j quarter (32 j) within chunk

    // copy this block's pre-packed table (overlaps other prologue loads)
    const unsigned int* Tp = Tp_g + (size_t)t*TPSZ;
    for (int s = tid; s < TPSZ/4; s += 512)
        ((uint4*)ldsu)[s] = ((const uint4*)Tp)[s];

    // t==0: encode this wg's own ka rows (4 rows x 512 j), row-local
    if (t == 0) {
        int erow = tid >> 7;                 // 0..3
        int ecol = (tid & 127) * 4;
        size_t ep = ((size_t)(b*512 + i0 + erow))*512 + ecol;
        float4 dv = *(const float4*)&dists[ep];
        uint4 eo;
        eo.x = kaenc(dv.x); eo.y = kaenc(dv.y); eo.z = kaenc(dv.z); eo.w = kaenc(dv.w);
        *(uint4*)&ka[ep] = eo;
    }

    // f staging: thread = (j0 = tid>>4, fq2 = tid&15); covers j = j0 + {0,32,64,96}.
    const int j0 = tid >> 4, fq2 = tid & 15;
    const uint2* fsrc0 = (const uint2*)f_in + ((size_t)b*512 + j0)*16 + fq2;
    const int fo_base = (j0 >> 1)*64 + fq2*4 + (j0 & 1)*2;
    unsigned int* fdstA = ldsu + FBASE + fo_base;
    unsigned int* fdstB = ldsu + FB2 + fo_base;
    // ka bases for the two rows this wave owns (8 j per group)
    const unsigned int* kab0 = &ka[((size_t)(b*512 + i0 + 2*rp))*512 + jq*32 + g*8];
    const unsigned int* kab1 = kab0 + 512;

    uint2 rb0, rb1, rb2, rb3;
    uint4 kc00, kc01, kc10, kc11, kn00, kn01, kn10, kn11;
    // prologue: chunk 0 f, write -> buf0; kq chunk0 (t>0 early, t==0 after barrier)
    {
        rb0 = fsrc0[0]; rb1 = fsrc0[512]; rb2 = fsrc0[1024]; rb3 = fsrc0[1536];
        if (t > 0) {
            kc00 = ((const uint4*)kab0)[0]; kc01 = ((const uint4*)kab0)[1];
            kc10 = ((const uint4*)kab1)[0]; kc11 = ((const uint4*)kab1)[1];
        }
        *(uint2*)fdstA = rb0; *(uint2*)(fdstA + 1024) = rb1;
        *(uint2*)(fdstA + 2048) = rb2; *(uint2*)(fdstA + 3072) = rb3;
    }
    __syncthreads();   // table + chunk 0 ready; vmcnt drained -> ka writes visible in-wg
    if (t == 0) {
        kc00 = ((const uint4*)kab0)[0]; kc01 = ((const uint4*)kab0)[1];
        kc10 = ((const uint4*)kab1)[0]; kc11 = ((const uint4*)kab1)[1];
    }

    const unsigned int* fpA = ldsu + FBASE + fq*4;
    const unsigned int* fpB = ldsu + FB2 + fq*4;
    const char* Tbyte = (const char*)ldsu + fq*16;
    const int jpb = jq*16 + g*4;      // f pair-index base for this group
    float a00 = 0.f, a01 = 0.f, a02 = 0.f, a03 = 0.f;   // row 2rp
    float a10 = 0.f, a11 = 0.f, a12 = 0.f, a13 = 0.f;   // row 2rp+1

    #pragma unroll
    for (int c = 0; c < 4; ++c) {
        if (c < 3) {  // prefetch next chunk's f and kq
            const uint2* sp = fsrc0 + (size_t)(c + 1)*2048;
            rb0 = sp[0]; rb1 = sp[512]; rb2 = sp[1024]; rb3 = sp[1536];
            const uint4* kp0 = (const uint4*)(kab0 + (c + 1)*128);
            const uint4* kp1 = (const uint4*)(kab1 + (c + 1)*128);
            kn00 = kp0[0]; kn01 = kp0[1];
            kn10 = kp1[0]; kn11 = kp1[1];
        }
        const unsigned int* fp = (c & 1) ? fpB : fpA;
        uint4 k0a[2] = {kc00, kc01};
        uint4 k1a[2] = {kc10, kc11};
        #pragma unroll
        for (int j4 = 0; j4 < 2; ++j4) {
            uint4 fA = *(const uint4*)&fp[(jpb + j4*2)*64];
            uint4 fB = *(const uint4*)&fp[(jpb + j4*2 + 1)*64];
            unsigned int kk0[4] = {k0a[j4].x, k0a[j4].y, k0a[j4].z, k0a[j4].w};
            unsigned int kk1[4] = {k1a[j4].x, k1a[j4].y, k1a[j4].z, k1a[j4].w};
            unsigned int fl_[8] = {fA.x, fA.y, fA.z, fA.w, fB.x, fB.y, fB.z, fB.w};
            #pragma unroll
            for (int u = 0; u < 4; ++u) {
                half2v f01 = __builtin_bit_cast(half2v, fl_[u*2]);
                half2v f23 = __builtin_bit_cast(half2v, fl_[u*2+1]);
                {   // row 2rp
                    unsigned int kau = kk0[u];
                    half2v av = __builtin_bit_cast(half2v, __builtin_amdgcn_perm(kau, kau, 0x01000100u));
                    uint4 tp = *(const uint4*)(Tbyte + (kau >> 16));
                    half2v W01 = __builtin_bit_cast(half2v, tp.z)*av + __builtin_bit_cast(half2v, tp.x);
                    half2v W23 = __builtin_bit_cast(half2v, tp.w)*av + __builtin_bit_cast(half2v, tp.y);
                    a00 += (float)W01[0] * (float)f01[0];
                    a01 += (float)W01[1] * (float)f01[1];
                    a02 += (float)W23[0] * (float)f23[0];
                    a03 += (float)W23[1] * (float)f23[1];
                }
                {   // row 2rp+1
                    unsigned int kau = kk1[u];
                    half2v av = __builtin_bit_cast(half2v, __builtin_amdgcn_perm(kau, kau, 0x01000100u));
                    uint4 tp = *(const uint4*)(Tbyte + (kau >> 16));
                    half2v W01 = __builtin_bit_cast(half2v, tp.z)*av + __builtin_bit_cast(half2v, tp.x);
                    half2v W23 = __builtin_bit_cast(half2v, tp.w)*av + __builtin_bit_cast(half2v, tp.y);
                    a10 += (float)W01[0] * (float)f01[0];
                    a11 += (float)W01[1] * (float)f01[1];
                    a12 += (float)W23[0] * (float)f23[0];
                    a13 += (float)W23[1] * (float)f23[1];
                }
            }
        }
        if (c < 3) {
            unsigned int* fd = (c & 1) ? fdstA : fdstB;
            *(uint2*)fd = rb0; *(uint2*)(fd + 1024) = rb1;
            *(uint2*)(fd + 2048) = rb2; *(uint2*)(fd + 3072) = rb3;
            kc00 = kn00; kc01 = kn01; kc10 = kn10; kc11 = kn11;
            __syncthreads();   // chunk c+1 visible to all
        }
    }
    // reduce over the 4 groups in-wave (j sub-ranges)
    a00 += __shfl_xor(a00, 16, 64); a00 += __shfl_xor(a00, 32, 64);
    a01 += __shfl_xor(a01, 16, 64); a01 += __shfl_xor(a01, 32, 64);
    a02 += __shfl_xor(a02, 16, 64); a02 += __shfl_xor(a02, 32, 64);
    a03 += __shfl_xor(a03, 16, 64); a03 += __shfl_xor(a03, 32, 64);
    a10 += __shfl_xor(a10, 16, 64); a10 += __shfl_xor(a10, 32, 64);
    a11 += __shfl_xor(a11, 16, 64); a11 += __shfl_xor(a11, 32, 64);
    a12 += __shfl_xor(a12, 16, 64); a12 += __shfl_xor(a12, 32, 64);
    a13 += __shfl_xor(a13, 16, 64); a13 += __shfl_xor(a13, 32, 64);

    __syncthreads();                  // all conv LDS reads done; regions reusable
    if (g == 0) {                     // per-wave partial rows -> scratch (buf1 region)
        float4 r0; r0.x = a00; r0.y = a01; r0.z = a02; r0.w = a03;
        float4 r1; r1.x = a10; r1.y = a11; r1.z = a12; r1.w = a13;
        *(float4*)&lds[YSCR + wave*128 + fq*4] = r0;
        *(float4*)&lds[YSCR + wave*128 + 64 + fq*4] = r1;
    }
    // stage post weights (table + buf0 regions are dead now)
    stageWT4(lds, 0, f2o + t*4096, tid);
    stageWT4(lds, 4096, dw + t*4096, tid);
    if (t < 2) {
        stageWT4(lds, 8192, in2f + (t+1)*4096, tid);
    } else {
        for (int s = tid; s < 1024; s += 512) {   // aw1^T dup to 64 rows, swizzled b128
            int quad = s >> 6, rr = s & 63;
            float4 v;
            v.x = aw1[(quad*4+0)*32 + (rr & 31)];
            v.y = aw1[(quad*4+1)*32 + (rr & 31)];
            v.z = aw1[(quad*4+2)*32 + (rr & 31)];
            v.w = aw1[(quad*4+3)*32 + (rr & 31)];
            *(float4*)&lds[8192 + rr*64 + (((quad + rr) & 15) << 2)] = v;
        }
    }
    if (tid < 64) {
        lds[12288 + tid] = f2b[t*64 + tid];
        lds[12352 + tid] = db[t*64 + tid];
        if (t == 2) {
            lds[12416 + tid] = ab1[tid & 31];
            lds[12480 + tid] = aw2[tid & 31];
        }
    }
    __syncthreads();

    if (wave < 4) {                   // row-local post: wave rt handles tile row rt
        int rt = wave;
        int grow = b*512 + i0 + rt;
        size_t ro = (size_t)grow*64 + lane;
        // row rt partials live in waves (rt>>1) + 2m, slot (rt&1)
        int wbase = (rt >> 1);
        float y = lds[YSCR + (wbase + 0)*128 + (rt & 1)*64 + lane]
                + lds[YSCR + (wbase + 2)*128 + (rt & 1)*64 + lane]
                + lds[YSCR + (wbase + 4)*128 + (rt & 1)*64 + lane]
                + lds[YSCR + (wbase + 6)*128 + (rt & 1)*64 + lane];
        float z = matvec64(lds, 0, y, lane) + lds[12288 + lane];
        float u = ssp(z);
        float y3 = matvec64(lds, 4096, u, lane) + lds[12352 + lane];
        float xin = (t == 0) ? emb[ro] : x_buf[ro];
        float xn = xin + y3;
        if (t < 2) {
            x_buf[ro] = xn;
            float fo = matvec64(lds, 8192, xn, lane);
            f_out[ro] = __builtin_bit_cast(unsigned short, (_Float16)fo);
        } else {
            float s1 = matvec64(lds, 8192, xn, lane) + lds[12416 + lane];
            float h = ssp(s1) * lds[12480 + lane];
            #pragma unroll
            for (int m = 1; m < 64; m <<= 1)
                h += __shfl_xor(h, m, 64);
            if (lane == 0) out[grow] = ab2[0] + 0.5f*h;   // lanes duplicate 32-dim h twice
        }
    }
}

extern "C" void kernel_launch(void* const* d_in, const int* in_sizes, int n_in,
                              void* d_out, int out_size, void* d_ws, size_t ws_size,
                              hipStream_t stream) {
    const float* emb  = (const float*)d_in[0];
    const float* dist = (const float*)d_in[1];
    const float* in2f = (const float*)d_in[2];
    const float* fw1  = (const float*)d_in[3];
    const float* fb1  = (const float*)d_in[4];
    const float* fw2  = (const float*)d_in[5];
    const float* fb2  = (const float*)d_in[6];
    const float* f2o  = (const float*)d_in[7];
    const float* f2b  = (const float*)d_in[8];
    const float* dwp  = (const float*)d_in[9];
    const float* dbp  = (const float*)d_in[10];
    const float* aw1  = (const float*)d_in[11];
    const float* ab1  = (const float*)d_in[12];
    const float* aw2  = (const float*)d_in[13];
    const float* ab2  = (const float*)d_in[14];
    float* out = (float*)d_out;
    float* ws = (float*)d_ws;
    unsigned int* Tp_g = (unsigned int*)ws;                  // 3*8704 = 26112 uints
    unsigned short* fA = (unsigned short*)(ws + 26112);      // 65536 float slots
    unsigned short* fB = (unsigned short*)(ws + 26112 + 65536);
    float* x_buf = ws + 26112 + 2*65536;                     // 131072 floats
    unsigned int* ka = (unsigned int*)(x_buf + 131072);      // 1048576 uints (4 MB)

    hipLaunchKernelGGL(schnet_pre0, dim3(176), dim3(512), 0, stream,
        emb, in2f, fw1, fb1, fw2, fb2, fA, Tp_g);
    hipLaunchKernelGGL(schnet_block, dim3(512), dim3(512), 0, stream,
        0, emb, dist, in2f, f2o, f2b, dwp, dbp, aw1, ab1, aw2, ab2,
        Tp_g, ka, fA, fB, x_buf, out);
    hipLaunchKernelGGL(schnet_block, dim3(512), dim3(512), 0, stream,
        1, emb, dist, in2f, f2o, f2b, dwp, dbp, aw1, ab1, aw2, ab2,
        Tp_g, ka, fB, fA, x_buf, out);
    hipLaunchKernelGGL(schnet_block, dim3(512), dim3(512), 0, stream,
        2, emb, dist, in2f, f2o, f2b, dwp, dbp, aw1, ab1, aw2, ab2,
        Tp_g, ka, fA, fB, x_buf, out);
}